// Round 2
// baseline (831.309 us; speedup 1.0000x reference)
//
#include <hip/hip_runtime.h>
#include <hip/hip_fp16.h>

#define DI __device__ __forceinline__

typedef _Float16 f16x8 __attribute__((ext_vector_type(8)));
typedef float f32x4 __attribute__((ext_vector_type(4)));

struct alignas(8) h4 { __half x, y, z, w; };

DI void async16(const void* g, void* l) {
  __builtin_amdgcn_global_load_lds(
      (__attribute__((address_space(1))) void*)g,
      (__attribute__((address_space(3))) void*)l, 16, 0, 0);
}

DI float waveReduceSum(float v) {
#pragma unroll
  for (int i = 1; i < 64; i <<= 1) v += __shfl_xor(v, i);
  return v;
}
DI float waveReduceMax(float v) {
#pragma unroll
  for (int i = 1; i < 64; i <<= 1) v = fmaxf(v, __shfl_xor(v, i));
  return v;
}

DI float gelu_exact(float x) { return 0.5f * x * (1.f + erff(x * 0.70710678118654752f)); }

// ---------------------------------------------------------------------------
// m97-style GEMM: C[M,N] = A[M,K] * Bt[N,K]^T (+bias), fp16 in, fp32 acc.
// 128x128 tile, BK=32, 256 threads (2x2 waves, each 4x4 of 16x16x32 MFMA).
// M,N divisible by 128; K divisible by 32. blockIdx.z = batch.
// BIAS: bias[col] added. BROW: bias[row] added (for transposed-output GEMMs).
// ---------------------------------------------------------------------------
template <typename CT, bool BIAS, bool BROW = false>
__global__ __launch_bounds__(256) void gemm_nt(
    const __half* __restrict__ A, const __half* __restrict__ Bt,
    const float* __restrict__ bias, CT* __restrict__ C,
    int M, int N, int K, long long sA, long long sB, long long sC) {
  __shared__ __align__(16) __half As[128 * 32];
  __shared__ __align__(16) __half Bs[128 * 32];

  const int tid = threadIdx.x;
  const int wave = tid >> 6, lane = tid & 63;
  A += (long long)blockIdx.z * sA;
  Bt += (long long)blockIdx.z * sB;
  C += (long long)blockIdx.z * sC;
  const int m0 = blockIdx.x * 128, n0 = blockIdx.y * 128;
  const int wm = wave & 1, wn = wave >> 1;

  f32x4 acc[4][4];
#pragma unroll
  for (int i = 0; i < 4; ++i)
#pragma unroll
    for (int j = 0; j < 4; ++j) acc[i][j] = (f32x4){0.f, 0.f, 0.f, 0.f};

  // staging: thread tid covers tile row tid>>2, 16B segment tid&3;
  // HW writes lane l of wave w at ldsbase(w) + l*16 == (tid>>2)*64 + (tid&3)*16
  const int r0 = tid >> 2;
  const int ks = (tid & 3) * 8;
  const __half* Ag0 = A + (size_t)(m0 + r0) * K + ks;
  const __half* Ag1 = Ag0 + (size_t)64 * K;
  const __half* Bg0 = Bt + (size_t)(n0 + r0) * K + ks;
  const __half* Bg1 = Bg0 + (size_t)64 * K;
  char* AsB0 = (char*)As + wave * 1024;
  char* AsB1 = AsB0 + 4096;
  char* BsB0 = (char*)Bs + wave * 1024;
  char* BsB1 = BsB0 + 4096;

  const __half* Ard = As + (wm * 64 + (lane & 15)) * 32 + (lane >> 4) * 8;
  const __half* Brd = Bs + (wn * 64 + (lane & 15)) * 32 + (lane >> 4) * 8;

  for (int k0 = 0; k0 < K; k0 += 32) {
    async16(Ag0 + k0, AsB0);
    async16(Ag1 + k0, AsB1);
    async16(Bg0 + k0, BsB0);
    async16(Bg1 + k0, BsB1);
    __syncthreads();  // compiler drains vmcnt(0) before s_barrier
    f16x8 af[4], bfr[4];
#pragma unroll
    for (int i = 0; i < 4; ++i) af[i] = *(const f16x8*)(Ard + i * 512);
#pragma unroll
    for (int j = 0; j < 4; ++j) bfr[j] = *(const f16x8*)(Brd + j * 512);
#pragma unroll
    for (int i = 0; i < 4; ++i)
#pragma unroll
      for (int j = 0; j < 4; ++j)
        acc[i][j] = __builtin_amdgcn_mfma_f32_16x16x32_f16(af[i], bfr[j], acc[i][j], 0, 0, 0);
    __syncthreads();
  }

  // epilogue: C/D layout col=lane&15, row=(lane>>4)*4+reg  [m89-verified]
  const int ln15 = lane & 15;
  const int q4 = lane >> 4;
#pragma unroll
  for (int j = 0; j < 4; ++j) {
    const int col = n0 + wn * 64 + j * 16 + ln15;
    const float bcol = BIAS ? bias[col] : 0.f;
#pragma unroll
    for (int i = 0; i < 4; ++i) {
      const int row = m0 + wm * 64 + i * 16 + q4 * 4;
#pragma unroll
      for (int r = 0; r < 4; ++r) {
        float v = acc[i][j][r] + bcol;
        if constexpr (BROW) v += bias[row + r];
        if constexpr (sizeof(CT) == 4)
          C[(size_t)(row + r) * N + col] = v;
        else
          C[(size_t)(row + r) * N + col] = __float2half(v);
      }
    }
  }
}

// ---------------------------------------------------------------------------
// Embedding gather + sinusoidal positional encoding; writes fp32 y and fp16 yh
// ---------------------------------------------------------------------------
__global__ __launch_bounds__(256) void embed_pos_kernel(
    const int* __restrict__ x, const float* __restrict__ emb,
    float* __restrict__ y, __half* __restrict__ yh) {
  const int row = blockIdx.x;  // b*1024 + s
  const int s = row & 1023;
  const int tok = x[row];
  const float* ep = emb + (size_t)tok * 768;
  float* yp = y + (size_t)row * 768;
  __half* hp = yh + (size_t)row * 768;
  const float c = -13.287712379549449f / 768.f;  // -log2(10000)/768
  for (int d = threadIdx.x; d < 768; d += 256) {
    float ang = (float)s * exp2f((float)d * c);
    float pe = (d & 1) ? cosf(ang) : sinf(ang);
    float v = ep[d] + pe;
    yp[d] = v;
    hp[d] = __float2half(v);
  }
}

// fp32 -> fp16 transposed copy (weights): out[c][r] = in[r][c], R,C mult of 32
__global__ __launch_bounds__(256) void transpose_f32_to_f16(
    const float* __restrict__ in, __half* __restrict__ out, int R, int C) {
  __shared__ float t[32][33];
  const int tx = threadIdx.x & 31, ty = threadIdx.x >> 5;
  const int c = blockIdx.x * 32 + tx;
  const int r0 = blockIdx.y * 32;
#pragma unroll
  for (int i = 0; i < 32; i += 8) t[ty + i][tx] = in[(size_t)(r0 + ty + i) * C + c];
  __syncthreads();
  const int oc = r0 + tx;
  const int o0 = blockIdx.x * 32;
#pragma unroll
  for (int i = 0; i < 32; i += 8)
    out[(size_t)(o0 + ty + i) * R + oc] = __float2half(t[tx][ty + i]);
}

// Row softmax over 1024 fp32 logits -> fp16 probs. One block per row.
__global__ __launch_bounds__(256) void softmax_rows(
    const float* __restrict__ L, __half* __restrict__ P) {
  const size_t row = blockIdx.x;
  const float4 x = ((const float4*)(L + row * 1024))[threadIdx.x];
  const int wave = threadIdx.x >> 6, lane = threadIdx.x & 63;
  float m = fmaxf(fmaxf(x.x, x.y), fmaxf(x.z, x.w));
  m = waveReduceMax(m);
  __shared__ float sm[4];
  __shared__ float ssum[4];
  if (lane == 0) sm[wave] = m;
  __syncthreads();
  m = fmaxf(fmaxf(sm[0], sm[1]), fmaxf(sm[2], sm[3]));
  float e0 = expf(x.x - m), e1 = expf(x.y - m), e2 = expf(x.z - m), e3 = expf(x.w - m);
  float s = e0 + e1 + e2 + e3;
  s = waveReduceSum(s);
  if (lane == 0) ssum[wave] = s;
  __syncthreads();
  s = ssum[0] + ssum[1] + ssum[2] + ssum[3];
  const float inv = 1.f / s;
  h4 o{__float2half(e0 * inv), __float2half(e1 * inv), __float2half(e2 * inv),
       __float2half(e3 * inv)};
  ((h4*)(P + row * 1024))[threadIdx.x] = o;
}

// y += (GELU? gelu(a) : a) in-place, plus partial sums for layernorm2d stats.
// grid = (96 chunks, 8 batches); each block handles 8192 contiguous floats.
template <bool GELU>
__global__ __launch_bounds__(256) void residual_stats(
    float* __restrict__ y, const float* __restrict__ a, float2* __restrict__ partials) {
  const int b = blockIdx.y, chunk = blockIdx.x;
  const size_t base = (size_t)b * 786432 + (size_t)chunk * 8192;
  float4* yp = (float4*)(y + base);
  const float4* ap = (const float4*)(a + base);
  float s = 0.f, ss = 0.f;
#pragma unroll
  for (int it = 0; it < 8; ++it) {
    const int idx = it * 256 + threadIdx.x;
    float4 yv = yp[idx];
    float4 av = ap[idx];
    if constexpr (GELU) {
      av.x = gelu_exact(av.x); av.y = gelu_exact(av.y);
      av.z = gelu_exact(av.z); av.w = gelu_exact(av.w);
    }
    float4 r{yv.x + av.x, yv.y + av.y, yv.z + av.z, yv.w + av.w};
    yp[idx] = r;
    s += r.x + r.y + r.z + r.w;
    ss += r.x * r.x + r.y * r.y + r.z * r.z + r.w * r.w;
  }
  s = waveReduceSum(s);
  ss = waveReduceSum(ss);
  __shared__ float2 wr[4];
  const int wave = threadIdx.x >> 6, lane = threadIdx.x & 63;
  if (lane == 0) wr[wave] = make_float2(s, ss);
  __syncthreads();
  if (threadIdx.x == 0) {
    float S = wr[0].x + wr[1].x + wr[2].x + wr[3].x;
    float SS = wr[0].y + wr[1].y + wr[2].y + wr[3].y;
    partials[b * 96 + chunk] = make_float2(S, SS);
  }
}

__global__ __launch_bounds__(64) void ln_finalize(
    const float2* __restrict__ partials, float2* __restrict__ mv) {
  const int b = blockIdx.x;
  const int t = threadIdx.x;
  float2 p = partials[b * 96 + t];
  float s = p.x, ss = p.y;
  if (t + 64 < 96) {
    float2 q = partials[b * 96 + t + 64];
    s += q.x;
    ss += q.y;
  }
  s = waveReduceSum(s);
  ss = waveReduceSum(ss);
  if (t == 0) {
    const float inv = 1.f / 786432.f;
    float mean = s * inv;
    float var = ss * inv - mean * mean;
    mv[b] = make_float2(mean, rsqrtf(var + 1e-5f));
  }
}

// y = (y - mean)*rstd*w + b  (w,b indexed [S,D], shared across batch);
// optionally also writes fp16 copy for the next GEMM.
template <bool WB>
__global__ __launch_bounds__(256) void ln_apply(
    float* __restrict__ y, __half* __restrict__ yh, const float* __restrict__ w,
    const float* __restrict__ bb, const float2* __restrict__ mv) {
  const unsigned i4 = blockIdx.x * 256 + threadIdx.x;  // float4 index
  const unsigned i = i4 * 4;
  const unsigned b = i / 786432u;
  const unsigned e4 = (i - b * 786432u) >> 2;
  const float2 m = mv[b];
  float4 yv = ((const float4*)y)[i4];
  const float4 wv = ((const float4*)w)[e4];
  const float4 bv = ((const float4*)bb)[e4];
  float4 r;
  r.x = (yv.x - m.x) * m.y * wv.x + bv.x;
  r.y = (yv.y - m.x) * m.y * wv.y + bv.y;
  r.z = (yv.z - m.x) * m.y * wv.z + bv.z;
  r.w = (yv.w - m.x) * m.y * wv.w + bv.w;
  ((float4*)y)[i4] = r;
  if constexpr (WB) {
    h4 o{__float2half(r.x), __float2half(r.y), __float2half(r.z), __float2half(r.w)};
    ((h4*)yh)[i4] = o;
  }
}

// ---------------------------------------------------------------------------
extern "C" void kernel_launch(void* const* d_in, const int* in_sizes, int n_in,
                              void* d_out, int out_size, void* d_ws, size_t ws_size,
                              hipStream_t stream) {
  const int* x = (const int*)d_in[0];
  const float* emb = (const float*)d_in[1];
  const float* Wq = (const float*)d_in[2];
  const float* bq = (const float*)d_in[3];
  const float* Wk = (const float*)d_in[4];
  const float* bk = (const float*)d_in[5];
  const float* Wv = (const float*)d_in[6];
  const float* bv = (const float*)d_in[7];
  const float* Wo = (const float*)d_in[8];
  const float* bo = (const float*)d_in[9];
  const float* W1 = (const float*)d_in[10];
  const float* b1 = (const float*)d_in[11];
  const float* W2 = (const float*)d_in[12];
  const float* b2 = (const float*)d_in[13];
  const float* ln1w = (const float*)d_in[14];
  const float* ln1b = (const float*)d_in[15];
  const float* ln2w = (const float*)d_in[16];
  const float* ln2b = (const float*)d_in[17];

  float* y = (float*)d_out;  // [8,1024,768] fp32 residual stream

  // ---- workspace map (liveness-based reuse), total ~228.1 MB ----
  char* ws = (char*)d_ws;
  __half* yh = (__half*)(ws + 0);               // 12.58 MB  fp16 residual stream
  __half* qb = (__half*)(ws + 12582912);        // 50.33 MB  q  -> av
  __half* kb = (__half*)(ws + 62914560);        // 50.33 MB  k  -> abuf (fp32, 25.2MB)
  float* abuf = (float*)kb;
  __half* vT = (__half*)(ws + 113246208);       // 50.33 MB  v^T -> ffn1
  float* Lg = (float*)(ws + 163577856);         // 33.55 MB  logits fp32
  __half* Ph = (__half*)(ws + 197132288);       // 16.78 MB  softmax probs fp16
  __half* slotA = (__half*)(ws + 213909504);    // 4.72 MB   weight^T rotation
  __half* slotB = (__half*)(ws + 218628096);
  __half* slotC = (__half*)(ws + 223346688);
  float2* part = (float2*)(ws + 228065280);     // 6.1 KB
  float2* mv = (float2*)(ws + 228071424);       // 64 B
  const size_t WS_NEEDED = 228071488;
  if (ws_size < WS_NEEDED) return;  // fail loud (absmax) rather than corrupt the queue

  const dim3 blk(256);
  const long long SH = 1024LL * 3072, SS = 1024LL * 1024, SY = 1024LL * 768;

  embed_pos_kernel<<<dim3(8192), blk, 0, stream>>>(x, emb, y, yh);

  // Q = y@Wq + bq  : [8192,768] x [3072,768]^T
  transpose_f32_to_f16<<<dim3(96, 24), blk, 0, stream>>>(Wq, slotA, 768, 3072);
  gemm_nt<__half, true><<<dim3(64, 24, 1), blk, 0, stream>>>(yh, slotA, bq, qb, 8192, 3072, 768, 0, 0, 0);
  // K
  transpose_f32_to_f16<<<dim3(96, 24), blk, 0, stream>>>(Wk, slotB, 768, 3072);
  gemm_nt<__half, true><<<dim3(64, 24, 1), blk, 0, stream>>>(yh, slotB, bk, kb, 8192, 3072, 768, 0, 0, 0);
  // V^T directly: vT[b][n][s] = sum_k Wv[k][n]*y[b][s][k] + bv[n]
  //   A = Wv^T fp16 [3072,768], Bt = y batch [1024,768], row-bias bv
  transpose_f32_to_f16<<<dim3(96, 24), blk, 0, stream>>>(Wv, slotC, 768, 3072);
  gemm_nt<__half, false, true><<<dim3(24, 8, 8), blk, 0, stream>>>(slotC, yh, bv, vT, 3072, 1024, 768, 0, SY, SH);

  // logits = q k^T (fp32), per batch
  gemm_nt<float, false><<<dim3(8, 8, 8), blk, 0, stream>>>(qb, kb, nullptr, Lg, 1024, 1024, 3072, SH, SH, SS);

  softmax_rows<<<dim3(8192), blk, 0, stream>>>(Lg, Ph);

  // av = P @ V  (Bt = V^T), per batch; write over q
  gemm_nt<__half, false><<<dim3(8, 24, 8), blk, 0, stream>>>(Ph, vT, nullptr, qb, 1024, 3072, 1024, SS, SH, SH);

  // a = av @ Wo + bo (fp32) -> abuf (over k)
  transpose_f32_to_f16<<<dim3(24, 96), blk, 0, stream>>>(Wo, slotA, 3072, 768);
  gemm_nt<float, true><<<dim3(64, 6, 1), blk, 0, stream>>>(qb, slotA, bo, abuf, 8192, 768, 3072, 0, 0, 0);

  // y = ln1(y + a)
  residual_stats<false><<<dim3(96, 8), blk, 0, stream>>>(y, abuf, part);
  ln_finalize<<<dim3(8), dim3(64), 0, stream>>>(part, mv);
  ln_apply<true><<<dim3(6144), blk, 0, stream>>>(y, yh, ln1w, ln1b, mv);

  // FFN: f1 = y@W1 + b1 (over vT), f = f1@W2 + b2 -> abuf
  transpose_f32_to_f16<<<dim3(96, 24), blk, 0, stream>>>(W1, slotB, 768, 3072);
  gemm_nt<__half, true><<<dim3(64, 24, 1), blk, 0, stream>>>(yh, slotB, b1, vT, 8192, 3072, 768, 0, 0, 0);
  transpose_f32_to_f16<<<dim3(24, 96), blk, 0, stream>>>(W2, slotC, 3072, 768);
  gemm_nt<float, true><<<dim3(64, 6, 1), blk, 0, stream>>>(vT, slotC, b2, abuf, 8192, 768, 3072, 0, 0, 0);

  // y = ln2(y + gelu(f))
  residual_stats<true><<<dim3(96, 8), blk, 0, stream>>>(y, abuf, part);
  ln_finalize<<<dim3(8), dim3(64), 0, stream>>>(part, mv);
  ln_apply<false><<<dim3(6144), blk, 0, stream>>>(y, nullptr, ln2w, ln2b, mv);
}

// Round 3
// 786.251 us; speedup vs baseline: 1.0573x; 1.0573x over previous
//
#include <hip/hip_runtime.h>
#include <hip/hip_fp16.h>

#define DI __device__ __forceinline__

typedef _Float16 f16x8 __attribute__((ext_vector_type(8)));
typedef float f32x4 __attribute__((ext_vector_type(4)));

struct alignas(8) h4 { __half x, y, z, w; };

DI void async16(const void* g, void* l) {
  __builtin_amdgcn_global_load_lds(
      (__attribute__((address_space(1))) void*)g,
      (__attribute__((address_space(3))) void*)l, 16, 0, 0);
}

DI float waveReduceSum(float v) {
#pragma unroll
  for (int i = 1; i < 64; i <<= 1) v += __shfl_xor(v, i);
  return v;
}
DI float waveReduceMax(float v) {
#pragma unroll
  for (int i = 1; i < 64; i <<= 1) v = fmaxf(v, __shfl_xor(v, i));
  return v;
}

DI float gelu_exact(float x) { return 0.5f * x * (1.f + erff(x * 0.70710678118654752f)); }

// ---------------------------------------------------------------------------
// GEMM: C[M,N] = A[M,K] * Bt[N,K]^T (+bias), fp16 in, fp32 acc.
// 128x128 tile, BK=64, 256 threads (2x2 waves, each 4x4 of 16x16x32 MFMA).
// 1-D grid mT*nT with GROUP_M=8 swizzle (mT must be divisible by 8).
// XOR-swizzled LDS chunk layout: global chunk (r,c) stored at slot (r, c^(r&7))
// so ds_read_b128 phases are 2-way bank aliased (free) instead of 8-way.
// BIAS: bias[col]. BROW: bias[row] (for transposed-output GEMMs).
// ---------------------------------------------------------------------------
template <typename CT, bool BIAS, bool BROW>
__global__ __launch_bounds__(256) void gemm_nt(
    const __half* __restrict__ A, int lda, long long sA,
    const __half* __restrict__ Bt, int ldb, long long sB,
    const float* __restrict__ bias, CT* __restrict__ C, int ldc, long long sC,
    int mT, int nT, int K) {
  __shared__ __align__(16) __half As[128 * 64];
  __shared__ __align__(16) __half Bs[128 * 64];

  const int tid = threadIdx.x;
  const int wave = tid >> 6, lane = tid & 63;

  // GROUP_M=8 swizzled block decode
  const int gsz = 8 * nT;
  const int g = blockIdx.x / gsz, r = blockIdx.x % gsz;
  const int m0 = (g * 8 + (r & 7)) * 128;
  const int n0 = (r >> 3) * 128;

  A += (long long)blockIdx.z * sA;
  Bt += (long long)blockIdx.z * sB;
  C += (long long)blockIdx.z * sC;
  const int wm = wave & 1, wn = wave >> 1;

  f32x4 acc[4][4];
#pragma unroll
  for (int i = 0; i < 4; ++i)
#pragma unroll
    for (int j = 0; j < 4; ++j) acc[i][j] = (f32x4){0.f, 0.f, 0.f, 0.f};

  // staging: instruction i of thread t fills LDS chunk (i*256+t); that slot
  // (row = i*32 + (t>>3), slotcol = t&7) holds global chunk col (t&7)^(row&7).
  const int srow = tid >> 3;                     // 0..31 (+32 per instruction)
  const int gc = (tid & 7) ^ (srow & 7);         // swizzled global chunk col
  const __half* Ag = A + (size_t)(m0 + srow) * lda + gc * 8;
  const __half* Bg = Bt + (size_t)(n0 + srow) * ldb + gc * 8;
  const size_t a32 = (size_t)32 * lda, b32 = (size_t)32 * ldb;
  char* AsW = (char*)As + wave * 1024;
  char* BsW = (char*)Bs + wave * 1024;

  const int ml = lane & 15, q = lane >> 4, lx = lane & 7;

  for (int k0 = 0; k0 < K; k0 += 64) {
#pragma unroll
    for (int i = 0; i < 4; ++i) {
      async16(Ag + i * a32 + k0, AsW + i * 4096);
      async16(Bg + i * b32 + k0, BsW + i * 4096);
    }
    __syncthreads();  // compiler drains vmcnt(0) before s_barrier
#pragma unroll
    for (int j = 0; j < 2; ++j) {  // two K=32 steps of the BK=64 tile
      f16x8 af[4], bf[4];
#pragma unroll
      for (int i = 0; i < 4; ++i) {
        af[i] = *(const f16x8*)(As + ((size_t)(wm * 64 + i * 16 + ml) * 8 + ((q + 4 * j) ^ lx)) * 8);
        bf[i] = *(const f16x8*)(Bs + ((size_t)(wn * 64 + i * 16 + ml) * 8 + ((q + 4 * j) ^ lx)) * 8);
      }
#pragma unroll
      for (int i = 0; i < 4; ++i)
#pragma unroll
        for (int jn = 0; jn < 4; ++jn)
          acc[i][jn] = __builtin_amdgcn_mfma_f32_16x16x32_f16(af[i], bf[jn], acc[i][jn], 0, 0, 0);
    }
    __syncthreads();
  }

  // epilogue: C/D layout col=lane&15, row=(lane>>4)*4+reg  [m89-verified]
#pragma unroll
  for (int j = 0; j < 4; ++j) {
    const int col = n0 + wn * 64 + j * 16 + ml;
    const float bcol = BIAS ? bias[col] : 0.f;
#pragma unroll
    for (int i = 0; i < 4; ++i) {
      const int row = m0 + wm * 64 + i * 16 + q * 4;
#pragma unroll
      for (int rr = 0; rr < 4; ++rr) {
        float v = acc[i][j][rr] + bcol;
        if constexpr (BROW) v += bias[row + rr];
        if constexpr (sizeof(CT) == 4)
          C[(size_t)(row + rr) * ldc + col] = v;
        else
          C[(size_t)(row + rr) * ldc + col] = __float2half(v);
      }
    }
  }
}

// ---------------------------------------------------------------------------
// Embedding gather + sinusoidal positional encoding; writes fp32 y and fp16 yh
// ---------------------------------------------------------------------------
__global__ __launch_bounds__(256) void embed_pos_kernel(
    const int* __restrict__ x, const float* __restrict__ emb,
    float* __restrict__ y, __half* __restrict__ yh) {
  const int row = blockIdx.x;  // b*1024 + s
  const int s = row & 1023;
  const int tok = x[row];
  const float* ep = emb + (size_t)tok * 768;
  float* yp = y + (size_t)row * 768;
  __half* hp = yh + (size_t)row * 768;
  const float c = -13.287712379549449f / 768.f;  // -log2(10000)/768
  for (int d = threadIdx.x; d < 768; d += 256) {
    float ang = (float)s * exp2f((float)d * c);
    float pe = (d & 1) ? cosf(ang) : sinf(ang);
    float v = ep[d] + pe;
    yp[d] = v;
    hp[d] = __float2half(v);
  }
}

// fp32 -> fp16 transposed copy (weights): out[c][r] = in[r][c], R,C mult of 32
__global__ __launch_bounds__(256) void transpose_f32_to_f16(
    const float* __restrict__ in, __half* __restrict__ out, int R, int C) {
  __shared__ float t[32][33];
  const int tx = threadIdx.x & 31, ty = threadIdx.x >> 5;
  const int c = blockIdx.x * 32 + tx;
  const int r0 = blockIdx.y * 32;
#pragma unroll
  for (int i = 0; i < 32; i += 8) t[ty + i][tx] = in[(size_t)(r0 + ty + i) * C + c];
  __syncthreads();
  const int oc = r0 + tx;
  const int o0 = blockIdx.x * 32;
#pragma unroll
  for (int i = 0; i < 32; i += 8)
    out[(size_t)(o0 + ty + i) * R + oc] = __float2half(t[tx][ty + i]);
}

// Row softmax over 1024 fp32 logits -> fp16 probs. One block per row.
__global__ __launch_bounds__(256) void softmax_rows(
    const float* __restrict__ L, __half* __restrict__ P) {
  const size_t row = blockIdx.x;
  const float4 x = ((const float4*)(L + row * 1024))[threadIdx.x];
  const int wave = threadIdx.x >> 6, lane = threadIdx.x & 63;
  float m = fmaxf(fmaxf(x.x, x.y), fmaxf(x.z, x.w));
  m = waveReduceMax(m);
  __shared__ float sm[4];
  __shared__ float ssum[4];
  if (lane == 0) sm[wave] = m;
  __syncthreads();
  m = fmaxf(fmaxf(sm[0], sm[1]), fmaxf(sm[2], sm[3]));
  float e0 = expf(x.x - m), e1 = expf(x.y - m), e2 = expf(x.z - m), e3 = expf(x.w - m);
  float s = e0 + e1 + e2 + e3;
  s = waveReduceSum(s);
  if (lane == 0) ssum[wave] = s;
  __syncthreads();
  s = ssum[0] + ssum[1] + ssum[2] + ssum[3];
  const float inv = 1.f / s;
  h4 o{__float2half(e0 * inv), __float2half(e1 * inv), __float2half(e2 * inv),
       __float2half(e3 * inv)};
  ((h4*)(P + row * 1024))[threadIdx.x] = o;
}

// y += (GELU? gelu(a) : a) in-place, plus partial sums for layernorm2d stats.
template <bool GELU>
__global__ __launch_bounds__(256) void residual_stats(
    float* __restrict__ y, const float* __restrict__ a, float2* __restrict__ partials) {
  const int b = blockIdx.y, chunk = blockIdx.x;
  const size_t base = (size_t)b * 786432 + (size_t)chunk * 8192;
  float4* yp = (float4*)(y + base);
  const float4* ap = (const float4*)(a + base);
  float s = 0.f, ss = 0.f;
#pragma unroll
  for (int it = 0; it < 8; ++it) {
    const int idx = it * 256 + threadIdx.x;
    float4 yv = yp[idx];
    float4 av = ap[idx];
    if constexpr (GELU) {
      av.x = gelu_exact(av.x); av.y = gelu_exact(av.y);
      av.z = gelu_exact(av.z); av.w = gelu_exact(av.w);
    }
    float4 r{yv.x + av.x, yv.y + av.y, yv.z + av.z, yv.w + av.w};
    yp[idx] = r;
    s += r.x + r.y + r.z + r.w;
    ss += r.x * r.x + r.y * r.y + r.z * r.z + r.w * r.w;
  }
  s = waveReduceSum(s);
  ss = waveReduceSum(ss);
  __shared__ float2 wr[4];
  const int wave = threadIdx.x >> 6, lane = threadIdx.x & 63;
  if (lane == 0) wr[wave] = make_float2(s, ss);
  __syncthreads();
  if (threadIdx.x == 0) {
    float S = wr[0].x + wr[1].x + wr[2].x + wr[3].x;
    float SS = wr[0].y + wr[1].y + wr[2].y + wr[3].y;
    partials[b * 96 + chunk] = make_float2(S, SS);
  }
}

__global__ __launch_bounds__(64) void ln_finalize(
    const float2* __restrict__ partials, float2* __restrict__ mv) {
  const int b = blockIdx.x;
  const int t = threadIdx.x;
  float2 p = partials[b * 96 + t];
  float s = p.x, ss = p.y;
  if (t + 64 < 96) {
    float2 qq = partials[b * 96 + t + 64];
    s += qq.x;
    ss += qq.y;
  }
  s = waveReduceSum(s);
  ss = waveReduceSum(ss);
  if (t == 0) {
    const float inv = 1.f / 786432.f;
    float mean = s * inv;
    float var = ss * inv - mean * mean;
    mv[b] = make_float2(mean, rsqrtf(var + 1e-5f));
  }
}

template <bool WB>
__global__ __launch_bounds__(256) void ln_apply(
    float* __restrict__ y, __half* __restrict__ yh, const float* __restrict__ w,
    const float* __restrict__ bb, const float2* __restrict__ mv) {
  const unsigned i4 = blockIdx.x * 256 + threadIdx.x;  // float4 index
  const unsigned i = i4 * 4;
  const unsigned b = i / 786432u;
  const unsigned e4 = (i - b * 786432u) >> 2;
  const float2 m = mv[b];
  float4 yv = ((const float4*)y)[i4];
  const float4 wv = ((const float4*)w)[e4];
  const float4 bv = ((const float4*)bb)[e4];
  float4 r;
  r.x = (yv.x - m.x) * m.y * wv.x + bv.x;
  r.y = (yv.y - m.x) * m.y * wv.y + bv.y;
  r.z = (yv.z - m.x) * m.y * wv.z + bv.z;
  r.w = (yv.w - m.x) * m.y * wv.w + bv.w;
  ((float4*)y)[i4] = r;
  if constexpr (WB) {
    h4 o{__float2half(r.x), __float2half(r.y), __float2half(r.z), __float2half(r.w)};
    ((h4*)yh)[i4] = o;
  }
}

// ---------------------------------------------------------------------------
extern "C" void kernel_launch(void* const* d_in, const int* in_sizes, int n_in,
                              void* d_out, int out_size, void* d_ws, size_t ws_size,
                              hipStream_t stream) {
  const int* x = (const int*)d_in[0];
  const float* emb = (const float*)d_in[1];
  const float* Wq = (const float*)d_in[2];
  const float* bq = (const float*)d_in[3];
  const float* Wk = (const float*)d_in[4];
  const float* bk = (const float*)d_in[5];
  const float* Wv = (const float*)d_in[6];
  const float* bv = (const float*)d_in[7];
  const float* Wo = (const float*)d_in[8];
  const float* bo = (const float*)d_in[9];
  const float* W1 = (const float*)d_in[10];
  const float* b1 = (const float*)d_in[11];
  const float* W2 = (const float*)d_in[12];
  const float* b2 = (const float*)d_in[13];
  const float* ln1w = (const float*)d_in[14];
  const float* ln1b = (const float*)d_in[15];
  const float* ln2w = (const float*)d_in[16];
  const float* ln2b = (const float*)d_in[17];

  float* y = (float*)d_out;  // [8,1024,768] fp32 residual stream

  // ---- workspace map (liveness reuse), total ~223.4 MB ----
  char* ws = (char*)d_ws;
  __half* yh = (__half*)(ws + 0);             // 12.58 MB fp16 residual stream
  __half* qk = (__half*)(ws + 12582912);      // 100.66 MB [8192,6144] q|k; av reuses
  __half* av = qk;                            //   av [8192,3072] fp16 (after logits)
  __half* vT = (__half*)(ws + 113246208);     // 50.33 MB v^T [8][3072][1024]
  float* abuf = (float*)vT;                   //   fp32 attn/ffn out (after PV)
  float* Lg = (float*)(ws + 163577856);       // 33.55 MB logits fp32
  __half* Ph = (__half*)(ws + 197132288);     // 16.78 MB probs fp16
  __half* f1 = (__half*)Lg;                   //   ffn hidden [8192,3072] (after PV)
  __half* wslot = (__half*)(ws + 213909504);  // 9.44 MB weight^T slot (rotating)
  float* bqk = (float*)(ws + 223346688);      // 24 KB concat bias q|k
  float2* part = (float2*)(ws + 223371264);   // 6.1 KB
  float2* mv = (float2*)(ws + 223377408);     // 64 B
  const size_t WS_NEEDED = 223377472;
  if (ws_size < WS_NEEDED) return;  // fail loud rather than corrupt the queue

  const dim3 blk(256);
  const long long SH = 1024LL * 3072, SS = 1024LL * 1024, SY = 1024LL * 768;
  const long long SQK = 1024LL * 6144;

  embed_pos_kernel<<<dim3(8192), blk, 0, stream>>>(x, emb, y, yh);

  // fused Q|K weights -> wslot [6144,768] fp16 ; bias concat
  transpose_f32_to_f16<<<dim3(96, 24), blk, 0, stream>>>(Wq, wslot, 768, 3072);
  transpose_f32_to_f16<<<dim3(96, 24), blk, 0, stream>>>(Wk, wslot + 3072 * 768, 768, 3072);
  hipMemcpyAsync(bqk, bq, 3072 * 4, hipMemcpyDeviceToDevice, stream);
  hipMemcpyAsync(bqk + 3072, bk, 3072 * 4, hipMemcpyDeviceToDevice, stream);

  // qk = yh @ [Wq|Wk] + [bq|bk] : [8192,768] x [6144,768]^T
  gemm_nt<__half, true, false><<<dim3(64 * 48, 1, 1), blk, 0, stream>>>(
      yh, 768, 0, wslot, 768, 0, bqk, qk, 6144, 0, 64, 48, 768);

  // vT[b][n][s] = sum_k Wv[k][n]*y[b][s][k] + bv[n]  (A=Wv^T, Bt=y batch, row bias)
  transpose_f32_to_f16<<<dim3(96, 24), blk, 0, stream>>>(Wv, wslot, 768, 3072);
  gemm_nt<__half, false, true><<<dim3(24 * 8, 1, 8), blk, 0, stream>>>(
      wslot, 768, 0, yh, 768, SY, bv, vT, 1024, SH, 24, 8, 768);

  // logits = q k^T (fp32), per batch; q/k are column slices of qk (lda 6144)
  gemm_nt<float, false, false><<<dim3(8 * 8, 1, 8), blk, 0, stream>>>(
      qk, 6144, SQK, qk + 3072, 6144, SQK, nullptr, Lg, 1024, SS, 8, 8, 3072);

  softmax_rows<<<dim3(8192), blk, 0, stream>>>(Lg, Ph);

  // av = P @ V (Bt = v^T), per batch; overwrites qk region
  gemm_nt<__half, false, false><<<dim3(8 * 24, 1, 8), blk, 0, stream>>>(
      Ph, 1024, SS, vT, 1024, SH, nullptr, av, 3072, SH, 8, 24, 1024);

  // a = av @ Wo + bo (fp32) -> abuf (over vT)
  transpose_f32_to_f16<<<dim3(24, 96), blk, 0, stream>>>(Wo, wslot, 3072, 768);
  gemm_nt<float, true, false><<<dim3(64 * 6, 1, 1), blk, 0, stream>>>(
      av, 3072, 0, wslot, 3072, 0, bo, abuf, 768, 0, 64, 6, 3072);

  // y = ln1(y + a)
  residual_stats<false><<<dim3(96, 8), blk, 0, stream>>>(y, abuf, part);
  ln_finalize<<<dim3(8), dim3(64), 0, stream>>>(part, mv);
  ln_apply<true><<<dim3(6144), blk, 0, stream>>>(y, yh, ln1w, ln1b, mv);

  // FFN: f1 = y@W1 + b1 (over Lg+Ph), f = f1@W2 + b2 -> abuf
  transpose_f32_to_f16<<<dim3(96, 24), blk, 0, stream>>>(W1, wslot, 768, 3072);
  gemm_nt<__half, true, false><<<dim3(64 * 24, 1, 1), blk, 0, stream>>>(
      yh, 768, 0, wslot, 768, 0, b1, f1, 3072, 0, 64, 24, 768);
  transpose_f32_to_f16<<<dim3(24, 96), blk, 0, stream>>>(W2, wslot, 3072, 768);
  gemm_nt<float, true, false><<<dim3(64 * 6, 1, 1), blk, 0, stream>>>(
      f1, 3072, 0, wslot, 3072, 0, b2, abuf, 768, 0, 64, 6, 3072);

  // y = ln2(y + gelu(f))
  residual_stats<true><<<dim3(96, 8), blk, 0, stream>>>(y, abuf, part);
  ln_finalize<<<dim3(8), dim3(64), 0, stream>>>(part, mv);
  ln_apply<false><<<dim3(6144), blk, 0, stream>>>(y, nullptr, ln2w, ln2b, mv);
}

// Round 4
// 749.393 us; speedup vs baseline: 1.1093x; 1.0492x over previous
//
#include <hip/hip_runtime.h>
#include <hip/hip_fp16.h>

#define DI __device__ __forceinline__

typedef _Float16 f16x8 __attribute__((ext_vector_type(8)));
typedef float f32x4 __attribute__((ext_vector_type(4)));

struct alignas(8) h4 { __half x, y, z, w; };

DI void async16(const void* g, void* l) {
  __builtin_amdgcn_global_load_lds(
      (__attribute__((address_space(1))) void*)g,
      (__attribute__((address_space(3))) void*)l, 16, 0, 0);
}

DI float waveReduceSum(float v) {
#pragma unroll
  for (int i = 1; i < 64; i <<= 1) v += __shfl_xor(v, i);
  return v;
}
DI float waveReduceMax(float v) {
#pragma unroll
  for (int i = 1; i < 64; i <<= 1) v = fmaxf(v, __shfl_xor(v, i));
  return v;
}

DI float gelu_exact(float x) { return 0.5f * x * (1.f + erff(x * 0.70710678118654752f)); }

// ---------------------------------------------------------------------------
// GEMM: C[M,N] = A[M,K] * Bt[N,K]^T (+bias), fp16 in, fp32 acc.
// 128x128 tile, BK=64, 256 threads (2x2 waves, each 4x4 of 16x16x32 MFMA).
// XCD-banded 1-D grid: xcd = blockIdx.x & 7 owns a private band of nb tiles
// (N-band if bandN, else M-band); within a band the other dim is chunked in
// groups of gm so the band's B (or A) slice stays L2-resident per XCD.
// XOR-swizzled LDS chunk layout (round-3 verified, 0 bank conflicts).
// blockIdx.z: batch or split-K index via strides sA/sB/sC/sBias.
// ---------------------------------------------------------------------------
template <typename CT, bool BIAS, bool BROW>
__global__ __launch_bounds__(256) void gemm_nt(
    const __half* __restrict__ A, int lda, long long sA,
    const __half* __restrict__ Bt, int ldb, long long sB,
    const float* __restrict__ bias, long long sBias,
    CT* __restrict__ C, int ldc, long long sC,
    int bandN, int nb, int gm, int K) {
  __shared__ __align__(16) __half As[128 * 64];
  __shared__ __align__(16) __half Bs[128 * 64];

  const int tid = threadIdx.x;
  const int wave = tid >> 6, lane = tid & 63;

  // XCD-banded block decode
  const int xcd = blockIdx.x & 7;
  const int j = blockIdx.x >> 3;
  const int per = nb * gm;
  const int grp = j / per, rem = j - grp * per;
  int m, n;
  if (bandN) { m = grp * gm + rem % gm; n = xcd * nb + rem / gm; }
  else       { n = grp * gm + rem % gm; m = xcd * nb + rem / gm; }
  const int m0 = m * 128, n0 = n * 128;

  A += (long long)blockIdx.z * sA;
  Bt += (long long)blockIdx.z * sB;
  C += (long long)blockIdx.z * sC;
  if constexpr (BIAS || BROW) bias += (long long)blockIdx.z * sBias;
  const int wm = wave & 1, wn = wave >> 1;

  f32x4 acc[4][4];
#pragma unroll
  for (int i = 0; i < 4; ++i)
#pragma unroll
    for (int jj = 0; jj < 4; ++jj) acc[i][jj] = (f32x4){0.f, 0.f, 0.f, 0.f};

  // staging: instruction i of thread t fills LDS chunk (i*256+t); slot
  // (row = i*32 + (t>>3), slotcol = t&7) holds global chunk col (t&7)^(row&7).
  const int srow = tid >> 3;
  const int gc = (tid & 7) ^ (srow & 7);
  const __half* Ag = A + (size_t)(m0 + srow) * lda + gc * 8;
  const __half* Bg = Bt + (size_t)(n0 + srow) * ldb + gc * 8;
  const size_t a32 = (size_t)32 * lda, b32 = (size_t)32 * ldb;
  char* AsW = (char*)As + wave * 1024;
  char* BsW = (char*)Bs + wave * 1024;

  const int ml = lane & 15, q = lane >> 4, lx = lane & 7;

  for (int k0 = 0; k0 < K; k0 += 64) {
#pragma unroll
    for (int i = 0; i < 4; ++i) {
      async16(Ag + i * a32 + k0, AsW + i * 4096);
      async16(Bg + i * b32 + k0, BsW + i * 4096);
    }
    __syncthreads();
#pragma unroll
    for (int jj = 0; jj < 2; ++jj) {  // two K=32 steps of the BK=64 tile
      f16x8 af[4], bf[4];
#pragma unroll
      for (int i = 0; i < 4; ++i) {
        af[i] = *(const f16x8*)(As + ((size_t)(wm * 64 + i * 16 + ml) * 8 + ((q + 4 * jj) ^ lx)) * 8);
        bf[i] = *(const f16x8*)(Bs + ((size_t)(wn * 64 + i * 16 + ml) * 8 + ((q + 4 * jj) ^ lx)) * 8);
      }
#pragma unroll
      for (int i = 0; i < 4; ++i)
#pragma unroll
        for (int jn = 0; jn < 4; ++jn)
          acc[i][jn] = __builtin_amdgcn_mfma_f32_16x16x32_f16(af[i], bf[jn], acc[i][jn], 0, 0, 0);
    }
    __syncthreads();
  }

  // epilogue: C/D layout col=lane&15, row=(lane>>4)*4+reg  [m89-verified]
#pragma unroll
  for (int jj = 0; jj < 4; ++jj) {
    const int col = n0 + wn * 64 + jj * 16 + ml;
    const float bcol = BIAS ? bias[col] : 0.f;
#pragma unroll
    for (int i = 0; i < 4; ++i) {
      const int row = m0 + wm * 64 + i * 16 + q * 4;
#pragma unroll
      for (int rr = 0; rr < 4; ++rr) {
        float v = acc[i][jj][rr] + bcol;
        if constexpr (BROW) v += bias[row + rr];
        if constexpr (sizeof(CT) == 4)
          C[(size_t)(row + rr) * ldc + col] = v;
        else
          C[(size_t)(row + rr) * ldc + col] = __float2half(v);
      }
    }
  }
}

// ---------------------------------------------------------------------------
// prep1: transpose Wq,Wk,Wv,W1 ([768,3072] fp32 -> [3072,768] fp16) + bias cat
// grid (2305, 4): x<2304 transposes tile, (x==2304, y==0) concats bq|bk.
// ---------------------------------------------------------------------------
__global__ __launch_bounds__(256) void prep1(
    const float* __restrict__ Wq, const float* __restrict__ Wk,
    const float* __restrict__ Wv, const float* __restrict__ W1,
    const float* __restrict__ bq, const float* __restrict__ bk,
    __half* __restrict__ wA, __half* __restrict__ wB, __half* __restrict__ wC,
    float* __restrict__ bqk) {
  if (blockIdx.x == 2304) {
    if (blockIdx.y == 0)
      for (int i = threadIdx.x; i < 3072; i += 256) {
        bqk[i] = bq[i];
        bqk[3072 + i] = bk[i];
      }
    return;
  }
  const float* in;
  __half* out;
  switch (blockIdx.y) {
    case 0: in = Wq; out = wA; break;
    case 1: in = Wk; out = wA + 3072 * 768; break;
    case 2: in = Wv; out = wB; break;
    default: in = W1; out = wC; break;
  }
  __shared__ float t[32][33];
  const int tx = threadIdx.x & 31, ty = threadIdx.x >> 5;
  const int cb = blockIdx.x % 96, rb = blockIdx.x / 96;  // C=3072, R=768
  const int c = cb * 32 + tx, r0 = rb * 32;
#pragma unroll
  for (int i = 0; i < 32; i += 8) t[ty + i][tx] = in[(size_t)(r0 + ty + i) * 3072 + c];
  __syncthreads();
  const int oc = r0 + tx, o0 = cb * 32;
#pragma unroll
  for (int i = 0; i < 32; i += 8)
    out[(size_t)(o0 + ty + i) * 768 + oc] = __float2half(t[tx][ty + i]);
}

// prep2: transpose Wo,W2 ([3072,768] fp32 -> [768,3072] fp16). grid (2304, 2).
__global__ __launch_bounds__(256) void prep2(
    const float* __restrict__ Wo, const float* __restrict__ W2, __half* __restrict__ wA) {
  const float* in = blockIdx.y ? W2 : Wo;
  __half* out = wA + (blockIdx.y ? 3072 * 768 : 0);
  __shared__ float t[32][33];
  const int tx = threadIdx.x & 31, ty = threadIdx.x >> 5;
  const int cb = blockIdx.x % 24, rb = blockIdx.x / 24;  // C=768, R=3072
  const int c = cb * 32 + tx, r0 = rb * 32;
#pragma unroll
  for (int i = 0; i < 32; i += 8) t[ty + i][tx] = in[(size_t)(r0 + ty + i) * 768 + c];
  __syncthreads();
  const int oc = r0 + tx, o0 = cb * 32;
#pragma unroll
  for (int i = 0; i < 32; i += 8)
    out[(size_t)(o0 + ty + i) * 3072 + oc] = __float2half(t[tx][ty + i]);
}

// ---------------------------------------------------------------------------
__global__ __launch_bounds__(256) void embed_pos_kernel(
    const int* __restrict__ x, const float* __restrict__ emb,
    float* __restrict__ y, __half* __restrict__ yh) {
  const int row = blockIdx.x;  // b*1024 + s
  const int s = row & 1023;
  const int tok = x[row];
  const float* ep = emb + (size_t)tok * 768;
  float* yp = y + (size_t)row * 768;
  __half* hp = yh + (size_t)row * 768;
  const float c = -13.287712379549449f / 768.f;  // -log2(10000)/768
  for (int d = threadIdx.x; d < 768; d += 256) {
    float ang = (float)s * exp2f((float)d * c);
    float pe = (d & 1) ? cosf(ang) : sinf(ang);
    float v = ep[d] + pe;
    yp[d] = v;
    hp[d] = __float2half(v);
  }
}

// Row softmax over 1024 fp32 logits -> fp16 probs. One block per row.
__global__ __launch_bounds__(256) void softmax_rows(
    const float* __restrict__ L, __half* __restrict__ P) {
  const size_t row = blockIdx.x;
  const float4 x = ((const float4*)(L + row * 1024))[threadIdx.x];
  const int wave = threadIdx.x >> 6, lane = threadIdx.x & 63;
  float m = fmaxf(fmaxf(x.x, x.y), fmaxf(x.z, x.w));
  m = waveReduceMax(m);
  __shared__ float sm[4];
  __shared__ float ssum[4];
  if (lane == 0) sm[wave] = m;
  __syncthreads();
  m = fmaxf(fmaxf(sm[0], sm[1]), fmaxf(sm[2], sm[3]));
  float e0 = expf(x.x - m), e1 = expf(x.y - m), e2 = expf(x.z - m), e3 = expf(x.w - m);
  float s = e0 + e1 + e2 + e3;
  s = waveReduceSum(s);
  if (lane == 0) ssum[wave] = s;
  __syncthreads();
  s = ssum[0] + ssum[1] + ssum[2] + ssum[3];
  const float inv = 1.f / s;
  h4 o{__float2half(e0 * inv), __float2half(e1 * inv), __float2half(e2 * inv),
       __float2half(e3 * inv)};
  ((h4*)(P + row * 1024))[threadIdx.x] = o;
}

// y += [gelu](p0 + p1 + bias[d]) in-place + layernorm2d partial sums.
// grid (96, 8): each block 8192 contiguous floats of batch blockIdx.y.
template <bool GELU>
__global__ __launch_bounds__(256) void residual_stats(
    float* __restrict__ y, const float* __restrict__ p0, const float* __restrict__ p1,
    const float* __restrict__ bias, float2* __restrict__ partials) {
  const int b = blockIdx.y, chunk = blockIdx.x;
  const size_t base = (size_t)b * 786432 + (size_t)chunk * 8192;
  float4* yp = (float4*)(y + base);
  const float4* a0 = (const float4*)(p0 + base);
  const float4* a1 = (const float4*)(p1 + base);
  float s = 0.f, ss = 0.f;
#pragma unroll
  for (int it = 0; it < 8; ++it) {
    const int idx = it * 256 + threadIdx.x;
    const int d = (chunk * 8192 + it * 1024 + threadIdx.x * 4) % 768;  // mult of 4
    float4 yv = yp[idx];
    float4 v0 = a0[idx];
    float4 v1 = a1[idx];
    const float4 bv = *(const float4*)(bias + d);
    float ax = v0.x + v1.x + bv.x, ay = v0.y + v1.y + bv.y;
    float az = v0.z + v1.z + bv.z, aw = v0.w + v1.w + bv.w;
    if constexpr (GELU) {
      ax = gelu_exact(ax); ay = gelu_exact(ay);
      az = gelu_exact(az); aw = gelu_exact(aw);
    }
    float4 r{yv.x + ax, yv.y + ay, yv.z + az, yv.w + aw};
    yp[idx] = r;
    s += r.x + r.y + r.z + r.w;
    ss += r.x * r.x + r.y * r.y + r.z * r.z + r.w * r.w;
  }
  s = waveReduceSum(s);
  ss = waveReduceSum(ss);
  __shared__ float2 wr[4];
  const int wave = threadIdx.x >> 6, lane = threadIdx.x & 63;
  if (lane == 0) wr[wave] = make_float2(s, ss);
  __syncthreads();
  if (threadIdx.x == 0) {
    float S = wr[0].x + wr[1].x + wr[2].x + wr[3].x;
    float SS = wr[0].y + wr[1].y + wr[2].y + wr[3].y;
    partials[b * 96 + chunk] = make_float2(S, SS);
  }
}

// Finalize (reduce 96 partials in-block) + apply LN; grid 6144 (768 blocks/batch).
template <bool WB>
__global__ __launch_bounds__(256) void ln_apply(
    float* __restrict__ y, __half* __restrict__ yh, const float* __restrict__ w,
    const float* __restrict__ bb, const float2* __restrict__ partials) {
  const unsigned i4 = blockIdx.x * 256 + threadIdx.x;  // float4 index
  const unsigned i = i4 * 4;
  const unsigned b = i / 786432u;  // uniform per block (1024 floats/block)
  const int tid = threadIdx.x;
  float s = 0.f, ss = 0.f;
  if (tid < 96) {
    float2 p = partials[b * 96 + tid];
    s = p.x;
    ss = p.y;
  }
  s = waveReduceSum(s);
  ss = waveReduceSum(ss);
  __shared__ float2 wsum[4];
  if ((tid & 63) == 0) wsum[tid >> 6] = make_float2(s, ss);
  __syncthreads();
  const float S = wsum[0].x + wsum[1].x + wsum[2].x + wsum[3].x;
  const float SS = wsum[0].y + wsum[1].y + wsum[2].y + wsum[3].y;
  const float inv = 1.f / 786432.f;
  const float mean = S * inv;
  const float rstd = rsqrtf(SS * inv - mean * mean + 1e-5f);

  const unsigned e4 = (i - b * 786432u) >> 2;
  float4 yv = ((const float4*)y)[i4];
  const float4 wv = ((const float4*)w)[e4];
  const float4 bv = ((const float4*)bb)[e4];
  float4 r;
  r.x = (yv.x - mean) * rstd * wv.x + bv.x;
  r.y = (yv.y - mean) * rstd * wv.y + bv.y;
  r.z = (yv.z - mean) * rstd * wv.z + bv.z;
  r.w = (yv.w - mean) * rstd * wv.w + bv.w;
  ((float4*)y)[i4] = r;
  if constexpr (WB) {
    h4 o{__float2half(r.x), __float2half(r.y), __float2half(r.z), __float2half(r.w)};
    ((h4*)yh)[i4] = o;
  }
}

// ---------------------------------------------------------------------------
extern "C" void kernel_launch(void* const* d_in, const int* in_sizes, int n_in,
                              void* d_out, int out_size, void* d_ws, size_t ws_size,
                              hipStream_t stream) {
  const int* x = (const int*)d_in[0];
  const float* emb = (const float*)d_in[1];
  const float* Wq = (const float*)d_in[2];
  const float* bq = (const float*)d_in[3];
  const float* Wk = (const float*)d_in[4];
  const float* bk = (const float*)d_in[5];
  const float* Wv = (const float*)d_in[6];
  const float* bv = (const float*)d_in[7];
  const float* Wo = (const float*)d_in[8];
  const float* bo = (const float*)d_in[9];
  const float* W1 = (const float*)d_in[10];
  const float* b1 = (const float*)d_in[11];
  const float* W2 = (const float*)d_in[12];
  const float* b2 = (const float*)d_in[13];
  const float* ln1w = (const float*)d_in[14];
  const float* ln1b = (const float*)d_in[15];
  const float* ln2w = (const float*)d_in[16];
  const float* ln2b = (const float*)d_in[17];

  float* y = (float*)d_out;  // [8,1024,768] fp32 residual stream

  // ---- workspace map (liveness overlays), total 216.04 MB ----
  char* ws = (char*)d_ws;
  __half* yh = (__half*)(ws + 0);            // 12.58 MB fp16 residual stream
  __half* qb = (__half*)(ws + 12582912);     // 50.33 MB q -> av -> f1
  __half* kb = (__half*)(ws + 62914560);     // 50.33 MB k -> Ph
  __half* Ph = kb;
  __half* vT = (__half*)(ws + 113246208);    // 50.33 MB v^T -> abuf (2x25.17 split-K)
  float* abuf = (float*)vT;
  float* Lg = (float*)(ws + 163577856);      // 33.55 MB logits fp32
  __half* wA = (__half*)(ws + 197132288);    // 9.44 MB Wq^T|Wk^T -> Wo^T|W2^T
  __half* wB = (__half*)(ws + 206569472);    // 4.72 MB Wv^T
  __half* wC = (__half*)(ws + 211288064);    // 4.72 MB W1^T
  float* bqk = (float*)(ws + 216006656);     // 24 KB bq|bk
  float2* part = (float2*)(ws + 216031232);  // 6 KB
  const size_t WS_NEEDED = 216037440;
  if (ws_size < WS_NEEDED) return;  // fail loud rather than corrupt the queue

  const dim3 blk(256);
  const long long SH = 1024LL * 3072, SS = 1024LL * 1024;
  const long long HALF = 25165824;  // q->k element stride (8192*3072)
  float* p1 = abuf + 6291456;       // second split-K partial

  prep1<<<dim3(2305, 4), blk, 0, stream>>>(Wq, Wk, Wv, W1, bq, bk, wA, wB, wC, bqk);
  embed_pos_kernel<<<dim3(8192), blk, 0, stream>>>(x, emb, y, yh);

  // q,k = yh @ {Wq,Wk} + {bq,bk}: z picks weight half / bias half / out buffer
  gemm_nt<__half, true, false><<<dim3(1536, 1, 2), blk, 0, stream>>>(
      yh, 768, 0, wA, 768, 3072LL * 768, bqk, 3072, qb, 3072, HALF, 1, 3, 8, 768);
  prep2<<<dim3(2304, 2), blk, 0, stream>>>(Wo, W2, wA);  // wA (QK weights) now dead

  // vT[b][n][s] = sum_k Wv[k][n]*y[b][s][k] + bv[n]  (A=Wv^T, Bt=y batch, row bias)
  gemm_nt<__half, false, true><<<dim3(192, 1, 8), blk, 0, stream>>>(
      wB, 768, 0, yh, 768, 1024LL * 768, bv, 0, vT, 1024, SH, 0, 3, 8, 768);

  // logits = q k^T (fp32), per batch
  gemm_nt<float, false, false><<<dim3(64, 1, 8), blk, 0, stream>>>(
      qb, 3072, SH, kb, 3072, SH, nullptr, 0, Lg, 1024, SS, 1, 1, 8, 3072);

  softmax_rows<<<dim3(8192), blk, 0, stream>>>(Lg, Ph);  // Ph overlays k (dead)

  // av = P @ V (Bt = v^T), per batch; av overlays q (dead)
  gemm_nt<__half, false, false><<<dim3(192, 1, 8), blk, 0, stream>>>(
      Ph, 1024, SS, vT, 1024, SH, nullptr, 0, (__half*)qb, 3072, SH, 1, 3, 8, 1024);

  // a = av @ Wo (split-K=2, partials; bias bo added in residual) -> abuf over vT
  gemm_nt<float, false, false><<<dim3(384, 1, 2), blk, 0, stream>>>(
      (__half*)qb, 3072, 1536, wA, 3072, 1536, nullptr, 0, abuf, 768, 6291456, 0, 8, 6, 1536);

  // y = ln1(y + a + bo)
  residual_stats<false><<<dim3(96, 8), blk, 0, stream>>>(y, abuf, p1, bo, part);
  ln_apply<true><<<dim3(6144), blk, 0, stream>>>(y, yh, ln1w, ln1b, part);

  // f1 = y@W1 + b1 -> overlays q/av (dead)
  gemm_nt<__half, true, false><<<dim3(1536, 1, 1), blk, 0, stream>>>(
      yh, 768, 0, wC, 768, 0, b1, 0, (__half*)qb, 3072, 0, 1, 3, 8, 768);
  // f = f1@W2 (split-K=2; bias b2 + gelu in residual) -> abuf
  gemm_nt<float, false, false><<<dim3(384, 1, 2), blk, 0, stream>>>(
      (__half*)qb, 3072, 1536, wA + 3072 * 768, 3072, 1536, nullptr, 0, abuf, 768, 6291456, 0, 8, 6, 1536);

  // y = ln2(y + gelu(f + b2))
  residual_stats<true><<<dim3(96, 8), blk, 0, stream>>>(y, abuf, p1, b2, part);
  ln_apply<false><<<dim3(6144), blk, 0, stream>>>(y, nullptr, ln2w, ln2b, part);
}

// Round 5
// 729.680 us; speedup vs baseline: 1.1393x; 1.0270x over previous
//
#include <hip/hip_runtime.h>
#include <hip/hip_fp16.h>

#define DI __device__ __forceinline__

typedef _Float16 f16x8 __attribute__((ext_vector_type(8)));
typedef float f32x4 __attribute__((ext_vector_type(4)));

struct alignas(8) h4 { __half x, y, z, w; };

DI void async16(const void* g, void* l) {
  __builtin_amdgcn_global_load_lds(
      (__attribute__((address_space(1))) void*)g,
      (__attribute__((address_space(3))) void*)l, 16, 0, 0);
}

DI float waveReduceSum(float v) {
#pragma unroll
  for (int i = 1; i < 64; i <<= 1) v += __shfl_xor(v, i);
  return v;
}
DI float waveReduceMax(float v) {
#pragma unroll
  for (int i = 1; i < 64; i <<= 1) v = fmaxf(v, __shfl_xor(v, i));
  return v;
}

DI float gelu_exact(float x) { return 0.5f * x * (1.f + erff(x * 0.70710678118654752f)); }

// ---------------------------------------------------------------------------
// GEMM: C[M,N] = A[M,K] * Bt[N,K]^T (+bias), fp16 in, fp32 acc.
// 128x128 tile, BK=64, 256 threads (2x2 waves, each 4x4 of 16x16x32 MFMA).
// R3-style GROUP_M=8 block swizzle (mT divisible by 8): spreads L2 misses in
// time — measured faster than XCD banding despite higher FETCH (R4 post-mortem).
// XOR-swizzled LDS chunk layout (0 bank conflicts, R3/R4-verified).
// blockIdx.z: batch or split-K index via strides sA/sB/sC/sBias.
// ---------------------------------------------------------------------------
template <typename CT, bool BIAS, bool BROW>
__global__ __launch_bounds__(256) void gemm_nt(
    const __half* __restrict__ A, int lda, long long sA,
    const __half* __restrict__ Bt, int ldb, long long sB,
    const float* __restrict__ bias, long long sBias,
    CT* __restrict__ C, int ldc, long long sC,
    int nT, int K) {
  __shared__ __align__(16) __half As[128 * 64];
  __shared__ __align__(16) __half Bs[128 * 64];

  const int tid = threadIdx.x;
  const int wave = tid >> 6, lane = tid & 63;

  // GROUP_M=8 swizzled block decode
  const int gsz = 8 * nT;
  const int g = blockIdx.x / gsz, r = blockIdx.x % gsz;
  const int m0 = (g * 8 + (r & 7)) * 128;
  const int n0 = (r >> 3) * 128;

  A += (long long)blockIdx.z * sA;
  Bt += (long long)blockIdx.z * sB;
  C += (long long)blockIdx.z * sC;
  if constexpr (BIAS || BROW) bias += (long long)blockIdx.z * sBias;
  const int wm = wave & 1, wn = wave >> 1;

  f32x4 acc[4][4];
#pragma unroll
  for (int i = 0; i < 4; ++i)
#pragma unroll
    for (int jj = 0; jj < 4; ++jj) acc[i][jj] = (f32x4){0.f, 0.f, 0.f, 0.f};

  // staging: instruction i of thread t fills LDS chunk (i*256+t); slot
  // (row = i*32 + (t>>3), slotcol = t&7) holds global chunk col (t&7)^(row&7).
  const int srow = tid >> 3;
  const int gc = (tid & 7) ^ (srow & 7);
  const __half* Ag = A + (size_t)(m0 + srow) * lda + gc * 8;
  const __half* Bg = Bt + (size_t)(n0 + srow) * ldb + gc * 8;
  const size_t a32 = (size_t)32 * lda, b32 = (size_t)32 * ldb;
  char* AsW = (char*)As + wave * 1024;
  char* BsW = (char*)Bs + wave * 1024;

  const int ml = lane & 15, q = lane >> 4, lx = lane & 7;
  // byte offset of this lane's j=0 fragment; j=1 differs only in chunk bit2 -> ^64
  const int aoff = ((wm * 64 + ml) * 8 + (q ^ lx)) * 16;
  const int boff = ((wn * 64 + ml) * 8 + (q ^ lx)) * 16;

  for (int k0 = 0; k0 < K; k0 += 64) {
#pragma unroll
    for (int i = 0; i < 4; ++i) {
      async16(Ag + i * a32 + k0, AsW + i * 4096);
      async16(Bg + i * b32 + k0, BsW + i * 4096);
    }
    __syncthreads();
#pragma unroll
    for (int jj = 0; jj < 2; ++jj) {  // two K=32 steps of the BK=64 tile
      const char* Ab = (const char*)As + (jj ? (aoff ^ 64) : aoff);
      const char* Bb = (const char*)Bs + (jj ? (boff ^ 64) : boff);
      f16x8 af[4], bf[4];
#pragma unroll
      for (int i = 0; i < 4; ++i) {
        af[i] = *(const f16x8*)(Ab + i * 2048);
        bf[i] = *(const f16x8*)(Bb + i * 2048);
      }
#pragma unroll
      for (int i = 0; i < 4; ++i)
#pragma unroll
        for (int jn = 0; jn < 4; ++jn)
          acc[i][jn] = __builtin_amdgcn_mfma_f32_16x16x32_f16(af[i], bf[jn], acc[i][jn], 0, 0, 0);
    }
    __syncthreads();
  }

  // epilogue: C/D layout col=lane&15, row=(lane>>4)*4+reg  [m89-verified]
#pragma unroll
  for (int jj = 0; jj < 4; ++jj) {
    const int col = n0 + wn * 64 + jj * 16 + ml;
    const float bcol = BIAS ? bias[col] : 0.f;
#pragma unroll
    for (int i = 0; i < 4; ++i) {
      const int row = m0 + wm * 64 + i * 16 + q * 4;
#pragma unroll
      for (int rr = 0; rr < 4; ++rr) {
        float v = acc[i][jj][rr] + bcol;
        if constexpr (BROW) v += bias[row + rr];
        if constexpr (sizeof(CT) == 4)
          C[(size_t)(row + rr) * ldc + col] = v;
        else
          C[(size_t)(row + rr) * ldc + col] = __float2half(v);
      }
    }
  }
}

// ---------------------------------------------------------------------------
// prep: all 6 weight transposes (fp32 -> fp16) + bias concat. grid (2305, 6).
// y=0..3: Wq,Wk,Wv,W1 [768,3072] -> [3072,768]; y=4,5: Wo,W2 [3072,768]->[768,3072].
// (x==2304, y==0): concat bq|bk.
// ---------------------------------------------------------------------------
__global__ __launch_bounds__(256) void prep(
    const float* __restrict__ Wq, const float* __restrict__ Wk,
    const float* __restrict__ Wv, const float* __restrict__ W1,
    const float* __restrict__ Wo, const float* __restrict__ W2,
    const float* __restrict__ bq, const float* __restrict__ bk,
    __half* __restrict__ wD, __half* __restrict__ wB, __half* __restrict__ wC,
    __half* __restrict__ wA, float* __restrict__ bqk) {
  if (blockIdx.x == 2304) {
    if (blockIdx.y == 0)
      for (int i = threadIdx.x; i < 3072; i += 256) {
        bqk[i] = bq[i];
        bqk[3072 + i] = bk[i];
      }
    return;
  }
  __shared__ float t[32][33];
  const int tx = threadIdx.x & 31, ty = threadIdx.x >> 5;
  if (blockIdx.y < 4) {
    const float* in;
    __half* out;
    switch (blockIdx.y) {
      case 0: in = Wq; out = wD; break;
      case 1: in = Wk; out = wD + 3072 * 768; break;
      case 2: in = Wv; out = wB; break;
      default: in = W1; out = wC; break;
    }
    const int cb = blockIdx.x % 96, rb = blockIdx.x / 96;  // C=3072, R=768
    const int c = cb * 32 + tx, r0 = rb * 32;
#pragma unroll
    for (int i = 0; i < 32; i += 8) t[ty + i][tx] = in[(size_t)(r0 + ty + i) * 3072 + c];
    __syncthreads();
    const int oc = r0 + tx, o0 = cb * 32;
#pragma unroll
    for (int i = 0; i < 32; i += 8)
      out[(size_t)(o0 + ty + i) * 768 + oc] = __float2half(t[tx][ty + i]);
  } else {
    const float* in = (blockIdx.y == 5) ? W2 : Wo;
    __half* out = wA + ((blockIdx.y == 5) ? 3072 * 768 : 0);
    const int cb = blockIdx.x % 24, rb = blockIdx.x / 24;  // C=768, R=3072
    const int c = cb * 32 + tx, r0 = rb * 32;
#pragma unroll
    for (int i = 0; i < 32; i += 8) t[ty + i][tx] = in[(size_t)(r0 + ty + i) * 768 + c];
    __syncthreads();
    const int oc = r0 + tx, o0 = cb * 32;
#pragma unroll
    for (int i = 0; i < 32; i += 8)
      out[(size_t)(o0 + ty + i) * 3072 + oc] = __float2half(t[tx][ty + i]);
  }
}

// ---------------------------------------------------------------------------
__global__ __launch_bounds__(256) void embed_pos_kernel(
    const int* __restrict__ x, const float* __restrict__ emb,
    float* __restrict__ y, __half* __restrict__ yh) {
  const int row = blockIdx.x;  // b*1024 + s
  const int s = row & 1023;
  const int tok = x[row];
  const float* ep = emb + (size_t)tok * 768;
  float* yp = y + (size_t)row * 768;
  __half* hp = yh + (size_t)row * 768;
  const float c = -13.287712379549449f / 768.f;  // -log2(10000)/768
  for (int d = threadIdx.x; d < 768; d += 256) {
    float ang = (float)s * exp2f((float)d * c);
    float pe = (d & 1) ? cosf(ang) : sinf(ang);
    float v = ep[d] + pe;
    yp[d] = v;
    hp[d] = __float2half(v);
  }
}

// Row softmax over 1024 fp32 logits -> fp16 probs. One block per row.
__global__ __launch_bounds__(256) void softmax_rows(
    const float* __restrict__ L, __half* __restrict__ P) {
  const size_t row = blockIdx.x;
  const float4 x = ((const float4*)(L + row * 1024))[threadIdx.x];
  const int wave = threadIdx.x >> 6, lane = threadIdx.x & 63;
  float m = fmaxf(fmaxf(x.x, x.y), fmaxf(x.z, x.w));
  m = waveReduceMax(m);
  __shared__ float sm[4];
  __shared__ float ssum[4];
  if (lane == 0) sm[wave] = m;
  __syncthreads();
  m = fmaxf(fmaxf(sm[0], sm[1]), fmaxf(sm[2], sm[3]));
  float e0 = expf(x.x - m), e1 = expf(x.y - m), e2 = expf(x.z - m), e3 = expf(x.w - m);
  float s = e0 + e1 + e2 + e3;
  s = waveReduceSum(s);
  if (lane == 0) ssum[wave] = s;
  __syncthreads();
  s = ssum[0] + ssum[1] + ssum[2] + ssum[3];
  const float inv = 1.f / s;
  h4 o{__float2half(e0 * inv), __float2half(e1 * inv), __float2half(e2 * inv),
       __float2half(e3 * inv)};
  ((h4*)(P + row * 1024))[threadIdx.x] = o;
}

// y += [gelu](p0 + p1 + bias[d]) in-place + layernorm2d partial sums.
// grid (96, 8): each block 8192 contiguous floats of batch blockIdx.y.
template <bool GELU>
__global__ __launch_bounds__(256) void residual_stats(
    float* __restrict__ y, const float* __restrict__ p0, const float* __restrict__ p1,
    const float* __restrict__ bias, float2* __restrict__ partials) {
  const int b = blockIdx.y, chunk = blockIdx.x;
  const size_t base = (size_t)b * 786432 + (size_t)chunk * 8192;
  float4* yp = (float4*)(y + base);
  const float4* a0 = (const float4*)(p0 + base);
  const float4* a1 = (const float4*)(p1 + base);
  float s = 0.f, ss = 0.f;
#pragma unroll
  for (int it = 0; it < 8; ++it) {
    const int idx = it * 256 + threadIdx.x;
    const int d = (chunk * 8192 + it * 1024 + threadIdx.x * 4) % 768;  // mult of 4
    float4 yv = yp[idx];
    float4 v0 = a0[idx];
    float4 v1 = a1[idx];
    const float4 bv = *(const float4*)(bias + d);
    float ax = v0.x + v1.x + bv.x, ay = v0.y + v1.y + bv.y;
    float az = v0.z + v1.z + bv.z, aw = v0.w + v1.w + bv.w;
    if constexpr (GELU) {
      ax = gelu_exact(ax); ay = gelu_exact(ay);
      az = gelu_exact(az); aw = gelu_exact(aw);
    }
    float4 r{yv.x + ax, yv.y + ay, yv.z + az, yv.w + aw};
    yp[idx] = r;
    s += r.x + r.y + r.z + r.w;
    ss += r.x * r.x + r.y * r.y + r.z * r.z + r.w * r.w;
  }
  s = waveReduceSum(s);
  ss = waveReduceSum(ss);
  __shared__ float2 wr[4];
  const int wave = threadIdx.x >> 6, lane = threadIdx.x & 63;
  if (lane == 0) wr[wave] = make_float2(s, ss);
  __syncthreads();
  if (threadIdx.x == 0) {
    float S = wr[0].x + wr[1].x + wr[2].x + wr[3].x;
    float SS = wr[0].y + wr[1].y + wr[2].y + wr[3].y;
    partials[b * 96 + chunk] = make_float2(S, SS);
  }
}

// Finalize (reduce 96 partials in-block) + apply LN; grid 6144 (768 blocks/batch).
template <bool WB>
__global__ __launch_bounds__(256) void ln_apply(
    float* __restrict__ y, __half* __restrict__ yh, const float* __restrict__ w,
    const float* __restrict__ bb, const float2* __restrict__ partials) {
  const unsigned i4 = blockIdx.x * 256 + threadIdx.x;  // float4 index
  const unsigned i = i4 * 4;
  const unsigned b = i / 786432u;  // uniform per block (1024 floats/block)
  const int tid = threadIdx.x;
  float s = 0.f, ss = 0.f;
  if (tid < 96) {
    float2 p = partials[b * 96 + tid];
    s = p.x;
    ss = p.y;
  }
  s = waveReduceSum(s);
  ss = waveReduceSum(ss);
  __shared__ float2 wsum[4];
  if ((tid & 63) == 0) wsum[tid >> 6] = make_float2(s, ss);
  __syncthreads();
  const float S = wsum[0].x + wsum[1].x + wsum[2].x + wsum[3].x;
  const float SS = wsum[0].y + wsum[1].y + wsum[2].y + wsum[3].y;
  const float inv = 1.f / 786432.f;
  const float mean = S * inv;
  const float rstd = rsqrtf(SS * inv - mean * mean + 1e-5f);

  const unsigned e4 = (i - b * 786432u) >> 2;
  float4 yv = ((const float4*)y)[i4];
  const float4 wv = ((const float4*)w)[e4];
  const float4 bv = ((const float4*)bb)[e4];
  float4 r;
  r.x = (yv.x - mean) * rstd * wv.x + bv.x;
  r.y = (yv.y - mean) * rstd * wv.y + bv.y;
  r.z = (yv.z - mean) * rstd * wv.z + bv.z;
  r.w = (yv.w - mean) * rstd * wv.w + bv.w;
  ((float4*)y)[i4] = r;
  if constexpr (WB) {
    h4 o{__float2half(r.x), __float2half(r.y), __float2half(r.z), __float2half(r.w)};
    ((h4*)yh)[i4] = o;
  }
}

// ---------------------------------------------------------------------------
extern "C" void kernel_launch(void* const* d_in, const int* in_sizes, int n_in,
                              void* d_out, int out_size, void* d_ws, size_t ws_size,
                              hipStream_t stream) {
  const int* x = (const int*)d_in[0];
  const float* emb = (const float*)d_in[1];
  const float* Wq = (const float*)d_in[2];
  const float* bq = (const float*)d_in[3];
  const float* Wk = (const float*)d_in[4];
  const float* bk = (const float*)d_in[5];
  const float* Wv = (const float*)d_in[6];
  const float* bv = (const float*)d_in[7];
  const float* Wo = (const float*)d_in[8];
  const float* bo = (const float*)d_in[9];
  const float* W1 = (const float*)d_in[10];
  const float* b1 = (const float*)d_in[11];
  const float* W2 = (const float*)d_in[12];
  const float* b2 = (const float*)d_in[13];
  const float* ln1w = (const float*)d_in[14];
  const float* ln1b = (const float*)d_in[15];
  const float* ln2w = (const float*)d_in[16];
  const float* ln2b = (const float*)d_in[17];

  float* y = (float*)d_out;  // [8,1024,768] fp32 residual stream

  // ---- workspace map (liveness overlays), total 225.5 MB (< 228.07 verified) ----
  char* ws = (char*)d_ws;
  __half* yh = (__half*)(ws + 0);            // 12.58 MB fp16 residual stream
  __half* qb = (__half*)(ws + 12582912);     // 50.33 MB q -> av -> f1
  __half* kb = (__half*)(ws + 62914560);     // 50.33 MB k -> Ph
  __half* Ph = kb;
  __half* vT = (__half*)(ws + 113246208);    // 50.33 MB v^T -> abuf (2x25.17 split-K)
  float* abuf = (float*)vT;
  float* Lg = (float*)(ws + 163577856);      // 33.55 MB logits fp32
  __half* wA = (__half*)(ws + 197132288);    // 9.44 MB Wo^T|W2^T
  __half* wD = (__half*)(ws + 206569472);    // 9.44 MB Wq^T|Wk^T
  __half* wB = (__half*)(ws + 216006656);    // 4.72 MB Wv^T
  __half* wC = (__half*)(ws + 220725248);    // 4.72 MB W1^T
  float* bqk = (float*)(ws + 225443840);     // 24 KB bq|bk
  float2* part = (float2*)(ws + 225468416);  // 6 KB
  const size_t WS_NEEDED = 225474624;
  if (ws_size < WS_NEEDED) return;  // fail loud rather than corrupt the queue

  const dim3 blk(256);
  const long long SH = 1024LL * 3072, SS = 1024LL * 1024;
  const long long HALF = 25165824;  // q->k element stride (8192*3072)
  float* p1 = abuf + 6291456;       // second split-K partial

  prep<<<dim3(2305, 6), blk, 0, stream>>>(Wq, Wk, Wv, W1, Wo, W2, bq, bk, wD, wB, wC, wA, bqk);
  embed_pos_kernel<<<dim3(8192), blk, 0, stream>>>(x, emb, y, yh);

  // q,k = yh @ {Wq,Wk} + {bq,bk}: z picks weight half / bias half / out buffer
  gemm_nt<__half, true, false><<<dim3(1536, 1, 2), blk, 0, stream>>>(
      yh, 768, 0, wD, 768, 3072LL * 768, bqk, 3072, qb, 3072, HALF, 24, 768);

  // vT[b][n][s] = sum_k Wv[k][n]*y[b][s][k] + bv[n]  (A=Wv^T, Bt=y batch, row bias)
  gemm_nt<__half, false, true><<<dim3(192, 1, 8), blk, 0, stream>>>(
      wB, 768, 0, yh, 768, 1024LL * 768, bv, 0, vT, 1024, SH, 8, 768);

  // logits = q k^T (fp32), per batch
  gemm_nt<float, false, false><<<dim3(64, 1, 8), blk, 0, stream>>>(
      qb, 3072, SH, kb, 3072, SH, nullptr, 0, Lg, 1024, SS, 8, 3072);

  softmax_rows<<<dim3(8192), blk, 0, stream>>>(Lg, Ph);  // Ph overlays k (dead)

  // av = P @ V (Bt = v^T), per batch; av overlays q (dead)
  gemm_nt<__half, false, false><<<dim3(192, 1, 8), blk, 0, stream>>>(
      Ph, 1024, SS, vT, 1024, SH, nullptr, 0, (__half*)qb, 3072, SH, 24, 1024);

  // a = av @ Wo (split-K=2, partials; bias bo added in residual) -> abuf over vT
  gemm_nt<float, false, false><<<dim3(384, 1, 2), blk, 0, stream>>>(
      (__half*)qb, 3072, 1536, wA, 3072, 1536, nullptr, 0, abuf, 768, 6291456, 6, 1536);

  // y = ln1(y + a + bo)
  residual_stats<false><<<dim3(96, 8), blk, 0, stream>>>(y, abuf, p1, bo, part);
  ln_apply<true><<<dim3(6144), blk, 0, stream>>>(y, yh, ln1w, ln1b, part);

  // f1 = y@W1 + b1 -> overlays q/av (dead)
  gemm_nt<__half, true, false><<<dim3(1536, 1, 1), blk, 0, stream>>>(
      yh, 768, 0, wC, 768, 0, b1, 0, (__half*)qb, 3072, 0, 24, 768);
  // f = f1@W2 (split-K=2; bias b2 + gelu in residual) -> abuf
  gemm_nt<float, false, false><<<dim3(384, 1, 2), blk, 0, stream>>>(
      (__half*)qb, 3072, 1536, wA + 3072 * 768, 3072, 1536, nullptr, 0, abuf, 768, 6291456, 6, 1536);

  // y = ln2(y + gelu(f + b2))
  residual_stats<true><<<dim3(96, 8), blk, 0, stream>>>(y, abuf, p1, b2, part);
  ln_apply<false><<<dim3(6144), blk, 0, stream>>>(y, nullptr, ln2w, ln2b, part);
}